// Round 1
// baseline (281.353 us; speedup 1.0000x reference)
//
#include <hip/hip_runtime.h>
#include <hip/hip_bf16.h>

typedef __bf16 bf16_t;
typedef __attribute__((ext_vector_type(8))) __bf16 bf16x8;
typedef __attribute__((ext_vector_type(4))) __bf16 bf16x4;
typedef __attribute__((ext_vector_type(4))) float f32x4;

#define MFMA16(a, b, c) __builtin_amdgcn_mfma_f32_16x16x32_bf16((a), (b), (c), 0, 0, 0)

// ---------------------------------------------------------------------------
// Kernel 1: QKV projection.  Out[m][n] = sum_k X[m][k] * W[n][k], output bf16.
// M = B*T = 32768, K = 1024, N = 128 per weight matrix.
// Block: 256 threads (4 waves, 2x2), tile 128x128, BK = 64, single-buffered LDS.
// blockIdx.y in {0,1,2} selects (Wq,Q), (Wk,K), (Wv,V).
// ---------------------------------------------------------------------------
__global__ __launch_bounds__(256, 2) void proj_qkv(
    const float* __restrict__ X,
    const float* __restrict__ W0, const float* __restrict__ W1, const float* __restrict__ W2,
    bf16_t* __restrict__ O0, bf16_t* __restrict__ O1, bf16_t* __restrict__ O2)
{
    // 128 rows x 64 bf16 = 128 B per row, XOR-swizzled within row.
    __shared__ __align__(16) char As[128 * 128];
    __shared__ __align__(16) char Bs[128 * 128];

    const int tid = threadIdx.x;
    const int wid = tid >> 6;
    const int lane = tid & 63;
    const int l15 = lane & 15, l4 = lane >> 4;
    const int wr = wid >> 1, wc = wid & 1;
    const int m0 = blockIdx.x * 128;

    const float* W = (blockIdx.y == 0) ? W0 : (blockIdx.y == 1 ? W1 : W2);
    bf16_t* O = (blockIdx.y == 0) ? O0 : (blockIdx.y == 1 ? O1 : O2);

    f32x4 acc[4][4] = {};

    for (int kb = 0; kb < 1024; kb += 64) {
        __syncthreads();
        // Stage A (x rows) and B (W rows): 128 rows x 64 k each, fp32 -> bf16.
        #pragma unroll
        for (int i = 0; i < 8; ++i) {
            int c = tid + i * 256;
            int r = c >> 4, kq = c & 15;   // kq indexes float4 chunks within the 64-k slab
            float4 xa = *(const float4*)(X + (size_t)(m0 + r) * 1024 + kb + kq * 4);
            bf16x4 av; av[0] = (bf16_t)xa.x; av[1] = (bf16_t)xa.y; av[2] = (bf16_t)xa.z; av[3] = (bf16_t)xa.w;
            *(bf16x4*)(As + r * 128 + ((kq * 8) ^ ((r & 7) << 4))) = av;
            float4 wa = *(const float4*)(W + (size_t)r * 1024 + kb + kq * 4);
            bf16x4 wv; wv[0] = (bf16_t)wa.x; wv[1] = (bf16_t)wa.y; wv[2] = (bf16_t)wa.z; wv[3] = (bf16_t)wa.w;
            *(bf16x4*)(Bs + r * 128 + ((kq * 8) ^ ((r & 7) << 4))) = wv;
        }
        __syncthreads();
        #pragma unroll
        for (int kk = 0; kk < 64; kk += 32) {
            const int kbyte = 2 * kk + 16 * l4;
            bf16x8 af[4], bfr[4];
            #pragma unroll
            for (int mi = 0; mi < 4; ++mi) {
                int r = wr * 64 + mi * 16 + l15;
                af[mi] = *(const bf16x8*)(As + r * 128 + (kbyte ^ ((r & 7) << 4)));
            }
            #pragma unroll
            for (int ni = 0; ni < 4; ++ni) {
                int r = wc * 64 + ni * 16 + l15;
                bfr[ni] = *(const bf16x8*)(Bs + r * 128 + (kbyte ^ ((r & 7) << 4)));
            }
            #pragma unroll
            for (int mi = 0; mi < 4; ++mi)
                #pragma unroll
                for (int ni = 0; ni < 4; ++ni)
                    acc[mi][ni] = MFMA16(af[mi], bfr[ni], acc[mi][ni]);
        }
    }

    // Epilogue: C/D layout col = lane&15, row = (lane>>4)*4 + r.
    #pragma unroll
    for (int mi = 0; mi < 4; ++mi)
        #pragma unroll
        for (int ni = 0; ni < 4; ++ni) {
            int row = m0 + wr * 64 + mi * 16 + l4 * 4;
            int col = wc * 64 + ni * 16 + l15;
            #pragma unroll
            for (int r = 0; r < 4; ++r)
                O[(size_t)(row + r) * 128 + col] = (bf16_t)acc[mi][ni][r];
        }
}

// ---------------------------------------------------------------------------
// Kernel 2: causal flash attention forward.
// Block: 256 threads (4 waves), QBLK = 64 (16 q-rows per wave), KVBLK = 64.
// Q frags in registers; K (row-major) and V^T in XOR-swizzled LDS;
// P round-trips through a small per-wave swizzled LDS buffer.
// Output fp32.
// ---------------------------------------------------------------------------
__global__ __launch_bounds__(256, 2) void attn_fwd(
    const bf16_t* __restrict__ Qb, const bf16_t* __restrict__ Kb, const bf16_t* __restrict__ Vb,
    float* __restrict__ out)
{
    __shared__ __align__(16) char Ks[64 * 256];    // [kv][h]: 64 rows x 128 bf16 (256 B rows)
    __shared__ __align__(16) char Vt[128 * 128];   // [h][kv]: 128 rows x 64 bf16 (128 B rows)
    __shared__ __align__(16) char Ps[4 * 16 * 128];// per-wave [q][kv]: 16 rows x 64 bf16

    const int tid = threadIdx.x, wid = tid >> 6, lane = tid & 63;
    const int l15 = lane & 15, l4 = lane >> 4;
    const int qt = gridDim.x - 1 - blockIdx.x;     // long blocks first
    const int b = blockIdx.y;
    const int q0 = qt * 64;
    const size_t base = (size_t)b * 4096 * 128;

    // Q fragments: row = q0 + wid*16 + (lane&15), k = kf*32 + 8*(lane>>4) + e
    bf16x8 aq[4];
    {
        const bf16_t* qp = Qb + base + (size_t)(q0 + wid * 16 + l15) * 128 + 8 * l4;
        #pragma unroll
        for (int kf = 0; kf < 4; ++kf) aq[kf] = *(const bf16x8*)(qp + kf * 32);
    }

    float mr[4], ls[4];
    #pragma unroll
    for (int r = 0; r < 4; ++r) { mr[r] = -1e30f; ls[r] = 0.f; }
    f32x4 o[8] = {};

    const float scale = 0.08838834764831845f;  // 1/sqrt(128)

    for (int kt = 0; kt <= qt; ++kt) {
        const int kv0 = kt * 64;
        __syncthreads();
        // Stage K tile: [kv][h] row-major, swizzled.
        #pragma unroll
        for (int i = 0; i < 4; ++i) {
            int c = tid + i * 256;
            int kv = c >> 4, hc = c & 15;
            bf16x8 kvv = *(const bf16x8*)(Kb + base + (size_t)(kv0 + kv) * 128 + hc * 8);
            *(bf16x8*)(Ks + kv * 256 + ((hc * 16) ^ ((kv & 7) << 4))) = kvv;
        }
        // Stage V^T tile: Vt[h][kv] = V[kv][h], swizzled, scalar writes.
        #pragma unroll
        for (int i = 0; i < 4; ++i) {
            int c = tid + i * 256;
            int kv = c & 63, h0 = (c >> 6) * 8;
            bf16x8 vv = *(const bf16x8*)(Vb + base + (size_t)(kv0 + kv) * 128 + h0);
            #pragma unroll
            for (int j = 0; j < 8; ++j)
                *(bf16_t*)(Vt + (h0 + j) * 128 + ((kv * 2) ^ (((h0 + j) & 7) << 4))) = vv[j];
        }
        __syncthreads();

        // S = Q K^T : S[q][kv], 4 kf x 4 ni MFMAs.
        f32x4 sa[4] = {};
        #pragma unroll
        for (int kf = 0; kf < 4; ++kf) {
            const int kbyte = kf * 64 + 16 * l4;
            #pragma unroll
            for (int ni = 0; ni < 4; ++ni) {
                int row = l15 + 16 * ni;
                bf16x8 bk = *(const bf16x8*)(Ks + row * 256 + (kbyte ^ ((row & 7) << 4)));
                sa[ni] = MFMA16(aq[kf], bk, sa[ni]);
            }
        }

        // Online softmax. Lane holds S[q = 4*l4 + r][kv = l15 + 16*ni].
        float p[4][4];
        float c_r[4];
        const int qg0 = q0 + wid * 16 + 4 * l4;
        #pragma unroll
        for (int r = 0; r < 4; ++r) {
            float tm = -1e30f;
            #pragma unroll
            for (int ni = 0; ni < 4; ++ni) {
                float sv = sa[ni][r] * scale;
                int kvg = kv0 + l15 + 16 * ni;
                if (kvg > qg0 + r) sv = -1e30f;   // causal mask
                p[ni][r] = sv;
                tm = fmaxf(tm, sv);
            }
            #pragma unroll
            for (int d = 1; d < 16; d <<= 1) tm = fmaxf(tm, __shfl_xor(tm, d, 64));
            float mnew = fmaxf(mr[r], tm);
            c_r[r] = __expf(mr[r] - mnew);
            float s = 0.f;
            #pragma unroll
            for (int ni = 0; ni < 4; ++ni) {
                float pv = __expf(p[ni][r] - mnew);
                p[ni][r] = pv;
                s += pv;
            }
            #pragma unroll
            for (int d = 1; d < 16; d <<= 1) s += __shfl_xor(s, d, 64);
            ls[r] = ls[r] * c_r[r] + s;
            mr[r] = mnew;
        }
        #pragma unroll
        for (int nf = 0; nf < 8; ++nf) {
            f32x4 t = o[nf];
            t[0] *= c_r[0]; t[1] *= c_r[1]; t[2] *= c_r[2]; t[3] *= c_r[3];
            o[nf] = t;
        }

        // Write P to per-wave LDS (swizzled), then read back in A-fragment layout.
        #pragma unroll
        for (int r = 0; r < 4; ++r) {
            int ql = 4 * l4 + r;
            char* pr = Ps + wid * 2048 + ql * 128;
            int xr = (ql & 7) << 4;
            #pragma unroll
            for (int ni = 0; ni < 4; ++ni) {
                int colb = (l15 + 16 * ni) * 2;
                *(bf16_t*)(pr + (colb ^ xr)) = (bf16_t)p[ni][r];
            }
        }
        __syncthreads();

        // O += P V : 2 kf x 8 nf MFMAs.
        #pragma unroll
        for (int kf = 0; kf < 2; ++kf) {
            const int kbyte = kf * 64 + 16 * l4;
            bf16x8 ap = *(const bf16x8*)(Ps + wid * 2048 + l15 * 128 + (kbyte ^ ((l15 & 7) << 4)));
            #pragma unroll
            for (int nf = 0; nf < 8; ++nf) {
                int h = l15 + 16 * nf;
                bf16x8 bv = *(const bf16x8*)(Vt + h * 128 + (kbyte ^ ((h & 7) << 4)));
                o[nf] = MFMA16(ap, bv, o[nf]);
            }
        }
    }

    // Epilogue: out[b][q][h] fp32, divide by softmax denominator.
    #pragma unroll
    for (int r = 0; r < 4; ++r) {
        float inv = 1.0f / ls[r];
        int qrow = q0 + wid * 16 + 4 * l4 + r;
        float* op = out + ((size_t)b * 4096 + qrow) * 128;
        #pragma unroll
        for (int nf = 0; nf < 8; ++nf)
            op[l15 + 16 * nf] = o[nf][r] * inv;
    }
}

extern "C" void kernel_launch(void* const* d_in, const int* in_sizes, int n_in,
                              void* d_out, int out_size, void* d_ws, size_t ws_size,
                              hipStream_t stream) {
    const float* X  = (const float*)d_in[0];
    const float* Wq = (const float*)d_in[1];
    const float* Wk = (const float*)d_in[2];
    const float* Wv = (const float*)d_in[3];
    float* out = (float*)d_out;

    const int M = in_sizes[0] / 1024;      // B*T = 32768
    const int Bn = M / 4096;               // 8

    bf16_t* Qb = (bf16_t*)d_ws;
    bf16_t* Kb = Qb + (size_t)M * 128;
    bf16_t* Vb = Kb + (size_t)M * 128;

    proj_qkv<<<dim3(M / 128, 3), 256, 0, stream>>>(X, Wq, Wk, Wv, Qb, Kb, Vb);
    attn_fwd<<<dim3(4096 / 64, Bn), 256, 0, stream>>>(Qb, Kb, Vb, out);
}

// Round 2
// 258.612 us; speedup vs baseline: 1.0879x; 1.0879x over previous
//
#include <hip/hip_runtime.h>
#include <hip/hip_bf16.h>

typedef __bf16 bf16_t;
typedef __attribute__((ext_vector_type(8))) __bf16 bf16x8;
typedef __attribute__((ext_vector_type(4))) __bf16 bf16x4;
typedef __attribute__((ext_vector_type(4))) float f32x4;

#define MFMA16(a, b, c) __builtin_amdgcn_mfma_f32_16x16x32_bf16((a), (b), (c), 0, 0, 0)

// ---------------------------------------------------------------------------
// Kernel 1: QKV projection.  Out[m][n] = sum_k X[m][k] * W[n][k].
// Q is pre-scaled by 1/sqrt(H); V is written TRANSPOSED as [b][h][t].
// ---------------------------------------------------------------------------
__global__ __launch_bounds__(256, 2) void proj_qkv(
    const float* __restrict__ X,
    const float* __restrict__ W0, const float* __restrict__ W1, const float* __restrict__ W2,
    bf16_t* __restrict__ O0, bf16_t* __restrict__ O1, bf16_t* __restrict__ O2)
{
    __shared__ __align__(16) char As[128 * 128];
    __shared__ __align__(16) char Bs[128 * 128];

    const int tid = threadIdx.x;
    const int wid = tid >> 6;
    const int lane = tid & 63;
    const int l15 = lane & 15, l4 = lane >> 4;
    const int wr = wid >> 1, wc = wid & 1;
    const int m0 = blockIdx.x * 128;

    const float* W = (blockIdx.y == 0) ? W0 : (blockIdx.y == 1 ? W1 : W2);

    f32x4 acc[4][4] = {};

    for (int kb = 0; kb < 1024; kb += 64) {
        __syncthreads();
        #pragma unroll
        for (int i = 0; i < 8; ++i) {
            int c = tid + i * 256;
            int r = c >> 4, kq = c & 15;
            float4 xa = *(const float4*)(X + (size_t)(m0 + r) * 1024 + kb + kq * 4);
            bf16x4 av; av[0] = (bf16_t)xa.x; av[1] = (bf16_t)xa.y; av[2] = (bf16_t)xa.z; av[3] = (bf16_t)xa.w;
            *(bf16x4*)(As + r * 128 + ((kq * 8) ^ ((r & 7) << 4))) = av;
            float4 wa = *(const float4*)(W + (size_t)r * 1024 + kb + kq * 4);
            bf16x4 wv; wv[0] = (bf16_t)wa.x; wv[1] = (bf16_t)wa.y; wv[2] = (bf16_t)wa.z; wv[3] = (bf16_t)wa.w;
            *(bf16x4*)(Bs + r * 128 + ((kq * 8) ^ ((r & 7) << 4))) = wv;
        }
        __syncthreads();
        #pragma unroll
        for (int kk = 0; kk < 64; kk += 32) {
            const int kbyte = 2 * kk + 16 * l4;
            bf16x8 af[4], bfr[4];
            #pragma unroll
            for (int mi = 0; mi < 4; ++mi) {
                int r = wr * 64 + mi * 16 + l15;
                af[mi] = *(const bf16x8*)(As + r * 128 + (kbyte ^ ((r & 7) << 4)));
            }
            #pragma unroll
            for (int ni = 0; ni < 4; ++ni) {
                int r = wc * 64 + ni * 16 + l15;
                bfr[ni] = *(const bf16x8*)(Bs + r * 128 + (kbyte ^ ((r & 7) << 4)));
            }
            #pragma unroll
            for (int mi = 0; mi < 4; ++mi)
                #pragma unroll
                for (int ni = 0; ni < 4; ++ni)
                    acc[mi][ni] = MFMA16(af[mi], bfr[ni], acc[mi][ni]);
        }
    }

    // Epilogue. C/D layout: col = lane&15, row = (lane>>4)*4 + r.
    if (blockIdx.y < 2) {
        const float sc = (blockIdx.y == 0) ? 0.08838834764831845f : 1.0f;  // fold 1/sqrt(128) into Q
        bf16_t* O = (blockIdx.y == 0) ? O0 : O1;
        #pragma unroll
        for (int mi = 0; mi < 4; ++mi)
            #pragma unroll
            for (int ni = 0; ni < 4; ++ni) {
                int row = m0 + wr * 64 + mi * 16 + l4 * 4;
                int col = wc * 64 + ni * 16 + l15;
                #pragma unroll
                for (int r = 0; r < 4; ++r)
                    O[(size_t)(row + r) * 128 + col] = (bf16_t)(acc[mi][ni][r] * sc);
            }
    } else {
        // V^T: [b][h][t], b = row>>12, t = row&4095; 4 consecutive rows -> contiguous t.
        #pragma unroll
        for (int mi = 0; mi < 4; ++mi)
            #pragma unroll
            for (int ni = 0; ni < 4; ++ni) {
                int row0 = m0 + wr * 64 + mi * 16 + l4 * 4;
                int col = wc * 64 + ni * 16 + l15;
                int bb = row0 >> 12, t0 = row0 & 4095;
                bf16x4 pk;
                #pragma unroll
                for (int r = 0; r < 4; ++r) pk[r] = (bf16_t)acc[mi][ni][r];
                *(bf16x4*)(O2 + ((size_t)bb << 19) + (size_t)col * 4096 + t0) = pk;
            }
    }
}

// ---------------------------------------------------------------------------
// Kernel 2: causal flash attention.
// 4 waves, QBLK=64 (16 q-rows/wave), KVBLK=128, single LDS buffer + T14
// register prefetch (issue next-tile loads before compute, write after barrier).
// Balanced block remap: co-resident pairs (L, L+256) handle q-tiles {x, 63-x}.
// ---------------------------------------------------------------------------
__global__ __launch_bounds__(256) void attn_fwd(
    const bf16_t* __restrict__ Qb, const bf16_t* __restrict__ Kb, const bf16_t* __restrict__ Vtg,
    float* __restrict__ out)
{
    __shared__ __align__(16) char Ks[128 * 256];   // [kv][h] swizzled, 32 KB
    __shared__ __align__(16) char Vt[128 * 256];   // [h][kv] swizzled, 32 KB
    __shared__ __align__(16) char Ps[4 * 16 * 256];// per-wave [q][kv], 16 KB

    const int tid = threadIdx.x, wid = tid >> 6, lane = tid & 63;
    const int l15 = lane & 15, l4 = lane >> 4;

    // Balanced remap: qt pairs summing to 63 land on (L, L+256).
    const int L = blockIdx.x + (blockIdx.y << 6);
    const int hh = L >> 8, rr = L & 255;
    const int b = rr >> 5, x5 = rr & 31;
    const int qt = hh ? (63 - x5) : x5;
    const int q0 = qt * 64;
    const int nt = (qt >> 1) + 1;                  // # of 128-wide kv tiles

    const size_t baseQK = (size_t)b * 4096 * 128;
    const size_t baseVT = (size_t)b << 19;

    // Q fragments (scale pre-folded): row = q0+wid*16+l15, k = kf*32+8*l4+e.
    bf16x8 aq[4];
    {
        const bf16_t* qp = Qb + baseQK + (size_t)(q0 + wid * 16 + l15) * 128 + 8 * l4;
        #pragma unroll
        for (int kf = 0; kf < 4; ++kf) aq[kf] = *(const bf16x8*)(qp + kf * 32);
    }

    float mr[4], ls[4];
    #pragma unroll
    for (int r = 0; r < 4; ++r) { mr[r] = -1e30f; ls[r] = 0.f; }
    f32x4 o[8] = {};

    // Staging thread map: 8 x b128 per thread for each of K and V^T.
    const int kr = tid >> 4;            // base row (kv for K, h for VT)
    const int kc = (tid & 15) * 8;      // elem offset within row
    bf16x8 pk[8], pv[8];

#define LOADT(KT) do {                                                                 \
        const int _kv0 = (KT) << 7;                                                    \
        _Pragma("unroll")                                                              \
        for (int i = 0; i < 8; ++i)                                                    \
            pk[i] = *(const bf16x8*)(Kb + baseQK + (size_t)(_kv0 + kr + i * 16) * 128 + kc); \
        _Pragma("unroll")                                                              \
        for (int i = 0; i < 8; ++i)                                                    \
            pv[i] = *(const bf16x8*)(Vtg + baseVT + (size_t)(kr + i * 16) * 4096 + _kv0 + kc); \
    } while (0)

#define WRITET() do {                                                                  \
        const int _xk = (kr & 7) << 4;                                                 \
        _Pragma("unroll")                                                              \
        for (int i = 0; i < 8; ++i)                                                    \
            *(bf16x8*)(Ks + (kr + i * 16) * 256 + ((kc * 2) ^ _xk)) = pk[i];           \
        _Pragma("unroll")                                                              \
        for (int i = 0; i < 8; ++i)                                                    \
            *(bf16x8*)(Vt + (kr + i * 16) * 256 + ((kc * 2) ^ _xk)) = pv[i];           \
    } while (0)

    LOADT(0);
    WRITET();
    __syncthreads();

    const int qg0 = q0 + wid * 16 + 4 * l4;
    char* pbase = Ps + wid * 4096;

    for (int kt = 0; kt < nt; ++kt) {
        const int kv0 = kt << 7;
        if (kt + 1 < nt) LOADT(kt + 1);   // hide global latency under compute

        // S = Q K^T  (S[q][kv], q = 4*l4+r, kv = l15+16*ni)
        f32x4 sa[8];
        #pragma unroll
        for (int ni = 0; ni < 8; ++ni) sa[ni] = (f32x4){0.f, 0.f, 0.f, 0.f};
        #pragma unroll
        for (int kf = 0; kf < 4; ++kf) {
            const int kb = kf * 64 + 16 * l4;
            #pragma unroll
            for (int ni = 0; ni < 8; ++ni) {
                int row = l15 + 16 * ni;
                bf16x8 bk = *(const bf16x8*)(Ks + row * 256 + (kb ^ ((row & 7) << 4)));
                sa[ni] = MFMA16(aq[kf], bk, sa[ni]);
            }
        }

        // Causal mask (only the last tile can touch the diagonal).
        if (kt == nt - 1) {
            #pragma unroll
            for (int ni = 0; ni < 8; ++ni)
                #pragma unroll
                for (int r = 0; r < 4; ++r)
                    if (kv0 + l15 + 16 * ni > qg0 + r) sa[ni][r] = -1e30f;
        }

        // Online softmax (16 lanes per q-row group; shfl within l15).
        float c_r[4];
        #pragma unroll
        for (int r = 0; r < 4; ++r) {
            float tm = sa[0][r];
            #pragma unroll
            for (int ni = 1; ni < 8; ++ni) tm = fmaxf(tm, sa[ni][r]);
            #pragma unroll
            for (int d = 1; d < 16; d <<= 1) tm = fmaxf(tm, __shfl_xor(tm, d, 64));
            float mnew = fmaxf(mr[r], tm);
            c_r[r] = __expf(mr[r] - mnew);
            float s = 0.f;
            #pragma unroll
            for (int ni = 0; ni < 8; ++ni) {
                float pvv = __expf(sa[ni][r] - mnew);
                sa[ni][r] = pvv;
                s += pvv;
            }
            #pragma unroll
            for (int d = 1; d < 16; d <<= 1) s += __shfl_xor(s, d, 64);
            ls[r] = ls[r] * c_r[r] + s;
            mr[r] = mnew;
        }
        #pragma unroll
        for (int nf = 0; nf < 8; ++nf) {
            f32x4 t = o[nf];
            t[0] *= c_r[0]; t[1] *= c_r[1]; t[2] *= c_r[2]; t[3] *= c_r[3];
            o[nf] = t;
        }

        // P -> per-wave LDS (wave-local; no block barrier needed).
        #pragma unroll
        for (int r = 0; r < 4; ++r) {
            int ql = 4 * l4 + r;
            char* prow = pbase + ql * 256;
            int xr = (ql & 7) << 4;
            #pragma unroll
            for (int ni = 0; ni < 8; ++ni)
                *(bf16_t*)(prow + (((l15 + 16 * ni) * 2) ^ xr)) = (bf16_t)sa[ni][r];
        }

        // O += P V
        #pragma unroll
        for (int kf = 0; kf < 4; ++kf) {
            const int kb = kf * 64 + 16 * l4;
            bf16x8 ap = *(const bf16x8*)(pbase + l15 * 256 + (kb ^ ((l15 & 7) << 4)));
            #pragma unroll
            for (int nf = 0; nf < 8; ++nf) {
                int hrow = l15 + 16 * nf;
                bf16x8 bv = *(const bf16x8*)(Vt + hrow * 256 + (kb ^ ((hrow & 7) << 4)));
                o[nf] = MFMA16(ap, bv, o[nf]);
            }
        }

        if (kt + 1 < nt) {
            __syncthreads();   // everyone done reading this tile
            WRITET();          // stage next tile (vmcnt wait auto-inserted)
            __syncthreads();   // next tile visible to all
        }
    }

    // Epilogue.
    #pragma unroll
    for (int r = 0; r < 4; ++r) {
        float inv = 1.0f / ls[r];
        int qrow = q0 + wid * 16 + 4 * l4 + r;
        float* op = out + ((size_t)b * 4096 + qrow) * 128;
        #pragma unroll
        for (int nf = 0; nf < 8; ++nf)
            op[l15 + 16 * nf] = o[nf][r] * inv;
    }
#undef LOADT
#undef WRITET
}

extern "C" void kernel_launch(void* const* d_in, const int* in_sizes, int n_in,
                              void* d_out, int out_size, void* d_ws, size_t ws_size,
                              hipStream_t stream) {
    const float* X  = (const float*)d_in[0];
    const float* Wq = (const float*)d_in[1];
    const float* Wk = (const float*)d_in[2];
    const float* Wv = (const float*)d_in[3];
    float* out = (float*)d_out;

    const int M = in_sizes[0] / 1024;      // B*T = 32768
    const int Bn = M / 4096;               // 8

    bf16_t* Qb  = (bf16_t*)d_ws;
    bf16_t* KbP = Qb + (size_t)M * 128;
    bf16_t* VtP = KbP + (size_t)M * 128;   // transposed: [b][128][4096]

    proj_qkv<<<dim3(M / 128, 3), 256, 0, stream>>>(X, Wq, Wk, Wv, Qb, KbP, VtP);
    attn_fwd<<<dim3(64, Bn), 256, 0, stream>>>(Qb, KbP, VtP, out);
}

// Round 3
// 178.426 us; speedup vs baseline: 1.5769x; 1.4494x over previous
//
#include <hip/hip_runtime.h>
#include <hip/hip_bf16.h>

typedef __bf16 bf16_t;
typedef __attribute__((ext_vector_type(8))) __bf16 bf16x8;
typedef __attribute__((ext_vector_type(4))) __bf16 bf16x4;
typedef __attribute__((ext_vector_type(4))) float f32x4;

#define MFMA16(a, b, c) __builtin_amdgcn_mfma_f32_16x16x32_bf16((a), (b), (c), 0, 0, 0)

__device__ __forceinline__ void gload_lds16(const void* g, void* l) {
    __builtin_amdgcn_global_load_lds(
        (const __attribute__((address_space(1))) void*)g,
        (__attribute__((address_space(3))) void*)l, 16, 0, 0);
}

// ---------------------------------------------------------------------------
// Kernel 1: QKV projection (unchanged, verified). Q pre-scaled by 1/sqrt(H);
// V written transposed as [b][h][t].
// ---------------------------------------------------------------------------
__global__ __launch_bounds__(256, 2) void proj_qkv(
    const float* __restrict__ X,
    const float* __restrict__ W0, const float* __restrict__ W1, const float* __restrict__ W2,
    bf16_t* __restrict__ O0, bf16_t* __restrict__ O1, bf16_t* __restrict__ O2)
{
    __shared__ __align__(16) char As[128 * 128];
    __shared__ __align__(16) char Bs[128 * 128];

    const int tid = threadIdx.x;
    const int wid = tid >> 6;
    const int lane = tid & 63;
    const int l15 = lane & 15, l4 = lane >> 4;
    const int wr = wid >> 1, wc = wid & 1;
    const int m0 = blockIdx.x * 128;

    const float* W = (blockIdx.y == 0) ? W0 : (blockIdx.y == 1 ? W1 : W2);

    f32x4 acc[4][4] = {};

    for (int kb = 0; kb < 1024; kb += 64) {
        __syncthreads();
        #pragma unroll
        for (int i = 0; i < 8; ++i) {
            int c = tid + i * 256;
            int r = c >> 4, kq = c & 15;
            float4 xa = *(const float4*)(X + (size_t)(m0 + r) * 1024 + kb + kq * 4);
            bf16x4 av; av[0] = (bf16_t)xa.x; av[1] = (bf16_t)xa.y; av[2] = (bf16_t)xa.z; av[3] = (bf16_t)xa.w;
            *(bf16x4*)(As + r * 128 + ((kq * 8) ^ ((r & 7) << 4))) = av;
            float4 wa = *(const float4*)(W + (size_t)r * 1024 + kb + kq * 4);
            bf16x4 wv; wv[0] = (bf16_t)wa.x; wv[1] = (bf16_t)wa.y; wv[2] = (bf16_t)wa.z; wv[3] = (bf16_t)wa.w;
            *(bf16x4*)(Bs + r * 128 + ((kq * 8) ^ ((r & 7) << 4))) = wv;
        }
        __syncthreads();
        #pragma unroll
        for (int kk = 0; kk < 64; kk += 32) {
            const int kbyte = 2 * kk + 16 * l4;
            bf16x8 af[4], bfr[4];
            #pragma unroll
            for (int mi = 0; mi < 4; ++mi) {
                int r = wr * 64 + mi * 16 + l15;
                af[mi] = *(const bf16x8*)(As + r * 128 + (kbyte ^ ((r & 7) << 4)));
            }
            #pragma unroll
            for (int ni = 0; ni < 4; ++ni) {
                int r = wc * 64 + ni * 16 + l15;
                bfr[ni] = *(const bf16x8*)(Bs + r * 128 + (kbyte ^ ((r & 7) << 4)));
            }
            #pragma unroll
            for (int mi = 0; mi < 4; ++mi)
                #pragma unroll
                for (int ni = 0; ni < 4; ++ni)
                    acc[mi][ni] = MFMA16(af[mi], bfr[ni], acc[mi][ni]);
        }
    }

    if (blockIdx.y < 2) {
        const float sc = (blockIdx.y == 0) ? 0.08838834764831845f : 1.0f;
        bf16_t* O = (blockIdx.y == 0) ? O0 : O1;
        #pragma unroll
        for (int mi = 0; mi < 4; ++mi)
            #pragma unroll
            for (int ni = 0; ni < 4; ++ni) {
                int row = m0 + wr * 64 + mi * 16 + l4 * 4;
                int col = wc * 64 + ni * 16 + l15;
                #pragma unroll
                for (int r = 0; r < 4; ++r)
                    O[(size_t)(row + r) * 128 + col] = (bf16_t)(acc[mi][ni][r] * sc);
            }
    } else {
        #pragma unroll
        for (int mi = 0; mi < 4; ++mi)
            #pragma unroll
            for (int ni = 0; ni < 4; ++ni) {
                int row0 = m0 + wr * 64 + mi * 16 + l4 * 4;
                int col = wc * 64 + ni * 16 + l15;
                int bb = row0 >> 12, t0 = row0 & 4095;
                bf16x4 pk;
                #pragma unroll
                for (int r = 0; r < 4; ++r) pk[r] = (bf16_t)acc[mi][ni][r];
                *(bf16x4*)(O2 + ((size_t)bb << 19) + (size_t)col * 4096 + t0) = pk;
            }
    }
}

// ---------------------------------------------------------------------------
// Kernel 2: causal flash attention, split-kv pairs.
// 4 waves = 2 pairs; pair A even 64-kv tiles, pair B odd tiles; each wave
// owns 32 q-rows (two 16-col MFMA sets), S^T = K*Q^T so softmax stats are
// lane-local (q = lane&15). End-of-block merge of the two online states.
// Staging via global_load_lds(16B) with pre-swizzled global addresses.
// ---------------------------------------------------------------------------
__global__ __launch_bounds__(256, 2) void attn_fwd(
    const bf16_t* __restrict__ Qb, const bf16_t* __restrict__ Kb,
    const bf16_t* __restrict__ Vtg, float* __restrict__ out, int Bn)
{
    // [0,16K) KsA | [16K,32K) VtA | [32K,48K) KsB | [48K,64K) VtB | [64K,80K) P(4K/wave)
    __shared__ __align__(16) char lds[81920];

    const int tid = threadIdx.x, wid = tid >> 6, lane = tid & 63;
    const int l15 = lane & 15, l4 = lane >> 4;
    const int pair = wid >> 1, qhalf = wid & 1;

    const int L = blockIdx.x;
    const int b = L % Bn;                 // XCD = L%8 = batch -> KV fits per-XCD L2
    const int j = L / Bn;
    const int qt = (j < 32) ? j : 95 - j; // pairing: (j, j+32) -> work sums constant
    const int q0 = qt << 6;
    const int steps = (qt >> 1) + 1;
    const int qw0 = q0 + 32 * qhalf;

    const size_t base = (size_t)b * 4096 * 128;

    // Q fragments (B-operand): col q = qw0+16qs+l15, k = 32kf+8l4+e. Pre-scaled.
    bf16x8 aq[2][4];
    #pragma unroll
    for (int qs = 0; qs < 2; ++qs)
        #pragma unroll
        for (int kf = 0; kf < 4; ++kf)
            aq[qs][kf] = *(const bf16x8*)(Qb + base + (size_t)(qw0 + 16 * qs + l15) * 128 + 32 * kf + 8 * l4);

    float mx[2] = {-1e30f, -1e30f}, lsum[2] = {0.f, 0.f};
    f32x4 o[2][8] = {};

    char* Kbuf = lds + pair * 32768;
    char* Vbuf = Kbuf + 16384;
    char* Pw   = lds + 65536 + wid * 4096;
    char* stg  = lds + wid * 16384;       // w0:KsA w1:VtA w2:KsB w3:VtB

    const int sK_r = lane >> 4, sK_c = (lane & 15) << 4;
    const int sV_r = lane >> 3, sV_c = (lane & 7) << 4;

    auto stage = [&](int s) {
        const int t = 2 * s + pair;
        if (t * 64 > q0 + 63) return;     // tile never used by this pair
        const int kv0s = t << 6;
        if ((wid & 1) == 0) {
            // K tile: [64 kv][128 k] bf16, rows 256B, XOR-swizzled via global src
            #pragma unroll
            for (int i = 0; i < 16; ++i) {
                const int row = i * 4 + sK_r;
                const bf16_t* src = Kb + base + (size_t)(kv0s + row) * 128
                                    + ((sK_c ^ ((row & 7) << 4)) >> 1);
                gload_lds16(src, stg + i * 1024);
            }
        } else {
            // V^T tile: [128 h][64 kv] bf16, rows 128B
            #pragma unroll
            for (int i = 0; i < 16; ++i) {
                const int h = i * 8 + sV_r;
                const bf16_t* src = Vtg + base + (size_t)h * 4096 + kv0s
                                    + ((sV_c ^ ((h & 7) << 4)) >> 1);
                gload_lds16(src, stg + i * 1024);
            }
        }
    };

    stage(0);
    __syncthreads();

    for (int s = 0; s < steps; ++s) {
        const int tw = 2 * s + pair;
        const int kv0 = tw << 6;
        if (kv0 <= qw0 + 31) {
            // S^T = K * Q^T : D row = kv-in-tile (4*l4+r), col = q (l15)
            f32x4 sa[2][4];
            #pragma unroll
            for (int qs = 0; qs < 2; ++qs)
                #pragma unroll
                for (int ni = 0; ni < 4; ++ni) sa[qs][ni] = (f32x4){0.f, 0.f, 0.f, 0.f};
            #pragma unroll
            for (int kf = 0; kf < 4; ++kf) {
                const int kb = 64 * kf + 16 * l4;
                #pragma unroll
                for (int ni = 0; ni < 4; ++ni) {
                    const int krow = 16 * ni + l15;
                    bf16x8 ak = *(const bf16x8*)(Kbuf + krow * 256 + (kb ^ ((krow & 7) << 4)));
                    sa[0][ni] = MFMA16(ak, aq[0][kf], sa[0][ni]);
                    sa[1][ni] = MFMA16(ak, aq[1][kf], sa[1][ni]);
                }
            }
            #pragma unroll
            for (int qs = 0; qs < 2; ++qs) {
                const int qg = qw0 + 16 * qs + l15;
                if (kv0 + 63 > qw0 + 16 * qs) {   // only near-diagonal tiles mask
                    #pragma unroll
                    for (int ni = 0; ni < 4; ++ni)
                        #pragma unroll
                        for (int r = 0; r < 4; ++r)
                            if (kv0 + 16 * ni + 4 * l4 + r > qg) sa[qs][ni][r] = -1e30f;
                }
                float tm = sa[qs][0][0];
                #pragma unroll
                for (int ni = 0; ni < 4; ++ni)
                    #pragma unroll
                    for (int r = 0; r < 4; ++r) tm = fmaxf(tm, sa[qs][ni][r]);
                tm = fmaxf(tm, __shfl_xor(tm, 16, 64));
                tm = fmaxf(tm, __shfl_xor(tm, 32, 64));
                const float mnew = fmaxf(mx[qs], tm);
                const float c = __expf(mx[qs] - mnew);
                float ssum = 0.f;
                #pragma unroll
                for (int ni = 0; ni < 4; ++ni)
                    #pragma unroll
                    for (int r = 0; r < 4; ++r) {
                        float pv = __expf(sa[qs][ni][r] - mnew);
                        sa[qs][ni][r] = pv;
                        ssum += pv;
                    }
                ssum += __shfl_xor(ssum, 16, 64);
                ssum += __shfl_xor(ssum, 32, 64);
                lsum[qs] = lsum[qs] * c + ssum;
                mx[qs] = mnew;
                #pragma unroll
                for (int mf = 0; mf < 8; ++mf) {
                    f32x4 t = o[qs][mf];
                    t[0] *= c; t[1] *= c; t[2] *= c; t[3] *= c;
                    o[qs][mf] = t;
                }
                // P[q][kv] b64 packed writes, swizzled
                const int rowb = (16 * qs + l15) * 128;
                const int swz = (l15 & 7) << 4;
                #pragma unroll
                for (int ni = 0; ni < 4; ++ni) {
                    bf16x4 pv;
                    pv[0] = (bf16_t)sa[qs][ni][0]; pv[1] = (bf16_t)sa[qs][ni][1];
                    pv[2] = (bf16_t)sa[qs][ni][2]; pv[3] = (bf16_t)sa[qs][ni][3];
                    *(bf16x4*)(Pw + rowb + ((32 * ni + 8 * l4) ^ swz)) = pv;
                }
            }
            // O^T += V^T * P^T : D row = h (4*l4+r in tile mf), col = q (l15)
            const int swzp = (l15 & 7) << 4;
            #pragma unroll
            for (int kfp = 0; kfp < 2; ++kfp) {
                const int kb = 64 * kfp + 16 * l4;
                bf16x8 p0 = *(const bf16x8*)(Pw + l15 * 128 + (kb ^ swzp));
                bf16x8 p1 = *(const bf16x8*)(Pw + (16 + l15) * 128 + (kb ^ swzp));
                #pragma unroll
                for (int mf = 0; mf < 8; ++mf) {
                    const int h = 16 * mf + l15;
                    bf16x8 av = *(const bf16x8*)(Vbuf + h * 128 + (kb ^ ((h & 7) << 4)));
                    o[0][mf] = MFMA16(av, p0, o[0][mf]);
                    o[1][mf] = MFMA16(av, p1, o[1][mf]);
                }
            }
        }
        if (s + 1 < steps) {
            __syncthreads();   // all reads of current tiles done
            stage(s + 1);
            __syncthreads();   // staged data visible (vmcnt drained at barrier)
        }
    }

    // Merge pair B's online state into pair A's, then store.
    __syncthreads();
    if (wid >= 2) {
        char* dst = lds + (wid - 2) * 16384;
        #pragma unroll
        for (int qs = 0; qs < 2; ++qs)
            #pragma unroll
            for (int mf = 0; mf < 8; ++mf)
                *(f32x4*)(dst + (qs * 8 + mf) * 1024 + lane * 16) = o[qs][mf];
        f32x4 st; st[0] = mx[0]; st[1] = lsum[0]; st[2] = mx[1]; st[3] = lsum[1];
        *(f32x4*)(lds + 32768 + (wid - 2) * 1024 + lane * 16) = st;
    }
    __syncthreads();
    if (wid < 2) {
        char* srcO = lds + wid * 16384;
        f32x4 st = *(const f32x4*)(lds + 32768 + wid * 1024 + lane * 16);
        #pragma unroll
        for (int qs = 0; qs < 2; ++qs) {
            const float mB = st[2 * qs], lB = st[2 * qs + 1];
            const float mm = fmaxf(mx[qs], mB);
            const float a = __expf(mx[qs] - mm), bb = __expf(mB - mm);
            const float linv = 1.f / (lsum[qs] * a + lB * bb);
            const int qg = qw0 + 16 * qs + l15;
            float* op = out + ((size_t)b * 4096 + qg) * 128;
            #pragma unroll
            for (int mf = 0; mf < 8; ++mf) {
                f32x4 ob = *(const f32x4*)(srcO + (qs * 8 + mf) * 1024 + lane * 16);
                f32x4 r;
                #pragma unroll
                for (int e = 0; e < 4; ++e) r[e] = (o[qs][mf][e] * a + ob[e] * bb) * linv;
                *(f32x4*)(op + 16 * mf + 4 * l4) = r;
            }
        }
    }
}

extern "C" void kernel_launch(void* const* d_in, const int* in_sizes, int n_in,
                              void* d_out, int out_size, void* d_ws, size_t ws_size,
                              hipStream_t stream) {
    const float* X  = (const float*)d_in[0];
    const float* Wq = (const float*)d_in[1];
    const float* Wk = (const float*)d_in[2];
    const float* Wv = (const float*)d_in[3];
    float* out = (float*)d_out;

    const int M = in_sizes[0] / 1024;      // B*T
    const int Bn = M / 4096;               // 8

    bf16_t* Qb  = (bf16_t*)d_ws;
    bf16_t* KbP = Qb + (size_t)M * 128;
    bf16_t* VtP = KbP + (size_t)M * 128;   // transposed: [b][128][4096]

    proj_qkv<<<dim3(M / 128, 3), 256, 0, stream>>>(X, Wq, Wk, Wv, Qb, KbP, VtP);
    attn_fwd<<<dim3(64 * Bn), 256, 0, stream>>>(Qb, KbP, VtP, out, Bn);
}